// Round 7
// baseline (500.866 us; speedup 1.0000x reference)
//
#include <hip/hip_runtime.h>
#include <hip/hip_bf16.h>

#define D_IN   256
#define D_HID  128
#define D_OUT_ 64
#define NGRAPH 16
#define BN_EPS 1e-5f
#define BNC    64             // BN partial-accumulator copies (contention /64)

#define SCAN_TPB 256
#define SCAN_VPT 4            // 1024 elements per block

typedef __attribute__((ext_vector_type(8))) short short8;
typedef __attribute__((ext_vector_type(4))) float floatx4;

// ---------------- helpers ----------------
__device__ __forceinline__ unsigned short f2bf(float x) {   // RNE f32->bf16
    unsigned u = __float_as_uint(x);
    return (unsigned short)((u + 0x7fffu + ((u >> 16) & 1u)) >> 16);
}
__device__ __forceinline__ unsigned pack2bf(float lo, float hi) {
    return (unsigned)f2bf(lo) | ((unsigned)f2bf(hi) << 16);
}
__device__ __forceinline__ void bf2_decode(unsigned u, float& lo, float& hi) {
    lo = __uint_as_float(u << 16);
    hi = __uint_as_float(u & 0xffff0000u);
}
// acc[0..7] += bf16x8(qv)   (h rows are pre-scaled by dinv[src] in the GEMM
// epilogue, so aggregation is an UNWEIGHTED sum — no dinv gather needed)
__device__ __forceinline__ void add8(float* acc, uint4 qv) {
    float f0,f1,f2,f3,f4,f5,f6,f7;
    bf2_decode(qv.x, f0, f1); bf2_decode(qv.y, f2, f3);
    bf2_decode(qv.z, f4, f5); bf2_decode(qv.w, f6, f7);
    acc[0]+=f0; acc[1]+=f1; acc[2]+=f2; acc[3]+=f3;
    acc[4]+=f4; acc[5]+=f5; acc[6]+=f6; acc[7]+=f7;
}

// ---------------- fused weight-prep + degree/rank count (block-split) ----------
// blocks [0,WB): W[K][NOUT] f32 -> Wt[NOUT][K] bf16 ; blocks [WB,..): deg+rank.
// NOTE: no __shared__ here — both halves run at full occupancy (r4 lesson:
// never block-split a big-LDS body with a latency-bound body).
__global__ void prep_count_kernel(const float* __restrict__ W1, const float* __restrict__ W2,
                                  const float* __restrict__ W3,
                                  unsigned short* __restrict__ Wt1,
                                  unsigned short* __restrict__ Wt2,
                                  unsigned short* __restrict__ Wt3, int WB,
                                  const int* __restrict__ dst, int E,
                                  int* __restrict__ deg, int* __restrict__ rank) {
    if ((int)blockIdx.x < WB) {
        int idx = blockIdx.x * 256 + threadIdx.x;
        const int S1 = D_IN * D_HID;          // 32768
        const int S2 = D_HID * D_HID;         // 16384
        const int S3 = D_HID * D_OUT_;        // 8192
        if (idx < S1) {
            int k = idx / D_HID, n = idx - k * D_HID;
            Wt1[(size_t)n * D_IN + k] = f2bf(W1[idx]);
        } else if (idx < S1 + S2) {
            int i = idx - S1;
            int k = i / D_HID, n = i - k * D_HID;
            Wt2[(size_t)n * D_HID + k] = f2bf(W2[i]);
        } else if (idx < S1 + S2 + S3) {
            int i = idx - S1 - S2;
            int k = i / D_OUT_, n = i - k * D_OUT_;
            Wt3[(size_t)n * D_HID + k] = f2bf(W3[i]);
        }
    } else {
        int e0 = ((int)blockIdx.x - WB) * (256 * 4) + threadIdx.x;
        int d[4];
        #pragma unroll
        for (int i = 0; i < 4; ++i) {
            int e = e0 + i * 256;
            if (e < E) d[i] = dst[e];
        }
        #pragma unroll
        for (int i = 0; i < 4; ++i) {
            int e = e0 + i * 256;
            if (e < E) rank[e] = atomicAdd(&deg[d[i]], 1);
        }
    }
}

// fused: dinv for 1024 nodes + block sum for the scan (both depend only on deg)
__global__ void dinv_bsum_kernel(const int* __restrict__ deg, int N,
                                 float* __restrict__ dinv, int* __restrict__ bsum) {
    __shared__ int red[SCAN_TPB];
    int t = threadIdx.x;
    int base = blockIdx.x * (SCAN_TPB * SCAN_VPT) + t;
    int s = 0;
    #pragma unroll
    for (int i = 0; i < SCAN_VPT; ++i) {
        int idx = base + i * SCAN_TPB;
        if (idx < N) {
            int d = deg[idx];
            dinv[idx] = rsqrtf((float)(d + 1));   // +1 self-loop
            s += d;
        }
    }
    red[t] = s;
    __syncthreads();
    for (int off = SCAN_TPB / 2; off > 0; off >>= 1) {
        if (t < off) red[t] += red[t + off];
        __syncthreads();
    }
    if (t == 0) bsum[blockIdx.x] = red[0];
}

__global__ void scan_bsum_kernel(const int* __restrict__ bsum, int NB,
                                 int* __restrict__ bprefix,
                                 int* __restrict__ rowstart, int N, int E) {
    __shared__ int part[SCAN_TPB];
    int t = threadIdx.x;
    int s = (t < NB) ? bsum[t] : 0;
    part[t] = s;
    __syncthreads();
    for (int off = 1; off < SCAN_TPB; off <<= 1) {
        int x = (t >= off) ? part[t - off] : 0;
        __syncthreads();
        part[t] += x;
        __syncthreads();
    }
    if (t < NB) bprefix[t] = part[t] - s;   // exclusive prefix of block sums
    if (t == 0) rowstart[N] = E;            // total degree == E analytically
}

__global__ void local_scan_kernel(const int* __restrict__ deg, int N,
                                  const int* __restrict__ bprefix,
                                  int* __restrict__ rowstart) {
    __shared__ int part[SCAN_TPB];
    int t = threadIdx.x;
    int base = blockIdx.x * (SCAN_TPB * SCAN_VPT) + t * SCAN_VPT;
    int v[SCAN_VPT];
    int s = 0;
    #pragma unroll
    for (int i = 0; i < SCAN_VPT; ++i) {
        v[i] = (base + i < N) ? deg[base + i] : 0;
        s += v[i];
    }
    part[t] = s;
    __syncthreads();
    for (int off = 1; off < SCAN_TPB; off <<= 1) {   // inclusive Hillis-Steele
        int x = (t >= off) ? part[t - off] : 0;
        __syncthreads();
        part[t] += x;
        __syncthreads();
    }
    int excl = part[t] - s + bprefix[blockIdx.x];
    #pragma unroll
    for (int i = 0; i < SCAN_VPT; ++i) {
        if (base + i < N) rowstart[base + i] = excl;
        excl += v[i];
    }
}

// ---- standalone atomic-free CSR scatter, 4 edges/thread (r2-proven) ----
__global__ void scatter_kernel(const int* __restrict__ src, const int* __restrict__ dst,
                               int E, const int* __restrict__ rowstart,
                               const int* __restrict__ rank, int* __restrict__ csr) {
    int e0 = blockIdx.x * (256 * 4) + threadIdx.x;
    int d[4], rk[4], sv[4], pos[4];
    #pragma unroll
    for (int i = 0; i < 4; ++i) {
        int e = e0 + i * 256;
        if (e < E) { d[i] = dst[e]; rk[i] = rank[e]; sv[i] = src[e]; }
    }
    #pragma unroll
    for (int i = 0; i < 4; ++i) {
        int e = e0 + i * 256;
        if (e < E) pos[i] = rowstart[d[i]];
    }
    #pragma unroll
    for (int i = 0; i < 4; ++i) {
        int e = e0 + i * 256;
        if (e < E) csr[pos[i] + rk[i]] = sv[i];   // no atomics
    }
}

// ---------------- MFMA GEMM body: Cb[M][NOUT] bf16 = act(A)[M][K] @ Wt^T * dscale --
// B (Wt) staged into LDS once per block with XOR bank-swizzle (byte ^= (n&7)<<4,
// both write and read sides — involution). Inner loop ds_read_b128 -> MFMA.
// Epilogue scales row v by dscale[v] (= dinv[v]) so the aggregation becomes an
// unweighted sum (no dinv gather per edge).
// FUSE: BN scale/shift from BNC-way partial sums/sumsq (written by agg) -> LDS.
// Layouts: A[m=lane&15][k=quad*8+j], B[k=quad*8+j][n=lane&15], C/D col=lane&15 row=quad*4+reg.
template<int K, int NOUT, int FUSE, int ABF16>
__device__ __forceinline__ void gemm_body(
        int bid, const void* __restrict__ Aptr, const unsigned short* __restrict__ Wt,
        unsigned short* __restrict__ Cb, int M, const float* __restrict__ dscale,
        const float* __restrict__ sums, const float* __restrict__ sumsq,
        const float* __restrict__ gam, const float* __restrict__ bet, float invN) {
    constexpr int NT = NOUT / 16;
    constexpr int KS = K / 32;
    constexpr int CHUNKS = NOUT * K / 8;      // 16B chunks of Wt
    constexpr int KROW16 = K / 8;             // chunks per Wt row
    __shared__ unsigned short s_wt[NOUT * K];
    __shared__ float s_sc[FUSE ? K : 1];
    __shared__ float s_sh[FUSE ? K : 1];

    int lane = threadIdx.x & 63;
    int wave = threadIdx.x >> 6;
    int col  = lane & 15;
    int quad = lane >> 4;
    int kq   = quad * 8;
    int row  = bid * 64 + wave * 16 + col;
    int rowc = min(row, M - 1);

    // ---- issue A loads FIRST (HBM latency overlaps staging + barrier) ----
    uint4  qa[ABF16 ? KS : 1];
    float4 a0[ABF16 ? 1 : KS], a1[ABF16 ? 1 : KS];
    if (ABF16) {
        const unsigned short* Ab = (const unsigned short*)Aptr;
        #pragma unroll
        for (int i = 0; i < KS; ++i)
            qa[i] = *(const uint4*)&Ab[(size_t)rowc * K + i * 32 + kq];
    } else {
        const float* Af = (const float*)Aptr;
        #pragma unroll
        for (int i = 0; i < KS; ++i) {
            a0[i] = *(const float4*)&Af[(size_t)rowc * K + i * 32 + kq];
            a1[i] = *(const float4*)&Af[(size_t)rowc * K + i * 32 + kq + 4];
        }
    }

    // ---- stage Wt -> LDS with XOR swizzle (read side matches) ----
    {
        const uint4* Wg = (const uint4*)Wt;
        #pragma unroll
        for (int it = 0; it < CHUNKS / 256; ++it) {
            int c = it * 256 + (int)threadIdx.x;
            uint4 v = Wg[c];
            int n = c / KROW16;                       // Wt row of this chunk
            unsigned byte = ((unsigned)c * 16u) ^ ((unsigned)(n & 7) << 4);
            *(uint4*)((char*)s_wt + byte) = v;
        }
    }
    if (FUSE) {
        int t = threadIdx.x;
        if (t < K) {
            // reduce the BNC partial copies (L2-hot, hidden under staging)
            float s = 0.f, q = 0.f;
            #pragma unroll 8
            for (int c = 0; c < BNC; ++c) {
                s += sums[c * K + t];
                q += sumsq[c * K + t];
            }
            float mu  = s * invN;
            float var = q * invN - mu * mu;
            float sc  = gam[t] * rsqrtf(var + BN_EPS);
            s_sc[t] = sc;
            s_sh[t] = fmaf(-mu, sc, bet[t]);
        }
    }
    __syncthreads();

    // ---- convert A (and apply BN+ReLU when FUSE) ----
    short8 afr[KS];
    if (ABF16) {
        #pragma unroll
        for (int i = 0; i < KS; ++i) {
            if (FUSE) {
                int kb = i * 32 + kq;
                float f0,f1,f2,f3,f4,f5,f6,f7;
                bf2_decode(qa[i].x, f0, f1); bf2_decode(qa[i].y, f2, f3);
                bf2_decode(qa[i].z, f4, f5); bf2_decode(qa[i].w, f6, f7);
                float4 sc0 = *(const float4*)&s_sc[kb];
                float4 sc1 = *(const float4*)&s_sc[kb + 4];
                float4 sh0 = *(const float4*)&s_sh[kb];
                float4 sh1 = *(const float4*)&s_sh[kb + 4];
                f0 = fmaxf(0.f, fmaf(f0, sc0.x, sh0.x));
                f1 = fmaxf(0.f, fmaf(f1, sc0.y, sh0.y));
                f2 = fmaxf(0.f, fmaf(f2, sc0.z, sh0.z));
                f3 = fmaxf(0.f, fmaf(f3, sc0.w, sh0.w));
                f4 = fmaxf(0.f, fmaf(f4, sc1.x, sh1.x));
                f5 = fmaxf(0.f, fmaf(f5, sc1.y, sh1.y));
                f6 = fmaxf(0.f, fmaf(f6, sc1.z, sh1.z));
                f7 = fmaxf(0.f, fmaf(f7, sc1.w, sh1.w));
                uint4 p;
                p.x = pack2bf(f0, f1); p.y = pack2bf(f2, f3);
                p.z = pack2bf(f4, f5); p.w = pack2bf(f6, f7);
                afr[i] = __builtin_bit_cast(short8, p);
            } else {
                afr[i] = __builtin_bit_cast(short8, qa[i]);
            }
        }
    } else {
        #pragma unroll
        for (int i = 0; i < KS; ++i) {
            uint4 p;
            p.x = pack2bf(a0[i].x, a0[i].y); p.y = pack2bf(a0[i].z, a0[i].w);
            p.z = pack2bf(a1[i].x, a1[i].y); p.w = pack2bf(a1[i].z, a1[i].w);
            afr[i] = __builtin_bit_cast(short8, p);
        }
    }

    floatx4 acc[NT];
    #pragma unroll
    for (int nt = 0; nt < NT; ++nt) acc[nt] = (floatx4){0.f, 0.f, 0.f, 0.f};

    // ---- inner loop: ds_read_b128 (swizzled) -> MFMA; pipelined via lgkmcnt ----
    #pragma unroll
    for (int i = 0; i < KS; ++i) {
        #pragma unroll
        for (int nt = 0; nt < NT; ++nt) {
            unsigned byte = ((unsigned)((nt * 16 + col) * K + i * 32 + kq)) * 2u;
            byte ^= (unsigned)(col & 7) << 4;      // (nt*16+col)&7 == col&7
            short8 bfrag = *(const short8*)((const char*)s_wt + byte);
            acc[nt] = __builtin_amdgcn_mfma_f32_16x16x32_bf16(afr[i], bfrag, acc[nt], 0, 0, 0);
        }
    }

    int obase = bid * 64 + wave * 16 + quad * 4;
    #pragma unroll
    for (int r = 0; r < 4; ++r) {
        int orow = obase + r;
        if (orow < M) {
            float ds = dscale[orow];
            #pragma unroll
            for (int nt = 0; nt < NT; ++nt)
                Cb[(size_t)orow * NOUT + nt * 16 + col] = f2bf(acc[nt][r] * ds);
        }
    }
}

template<int K, int NOUT, int FUSE, int ABF16>
__global__ __launch_bounds__(256, 2) void gemm_mfma_kernel(
        const void* __restrict__ Aptr, const unsigned short* __restrict__ Wt,
        unsigned short* __restrict__ Cb, int M, const float* __restrict__ dscale,
        const float* __restrict__ sums, const float* __restrict__ sumsq,
        const float* __restrict__ gam, const float* __restrict__ bet, float invN) {
    gemm_body<K, NOUT, FUSE, ABF16>(blockIdx.x, Aptr, Wt, Cb, M, dscale,
                                    sums, sumsq, gam, bet, invN);
}

// ---------------- Aggregation (pre-scaled bf16 h, bf16 out, 4B CSR) ---------------
// out[v] = dinv[v] * (h[v] + sum_{s in N(v)} h[s]) + bias     (h pre-scaled by dinv)
// BNS=1 (D=128 only): ALSO accumulate BN sum/sumsq partials — wave-local
// __shfl_xor reduce (NO barrier; r3 lesson) + atomics spread over BNC copies
// (contention /64 vs r3). Stats from pre-rounding f32 (r3 precedent).
template<int D, int BNS>
__global__ __launch_bounds__(256) void agg_bf16_kernel(
        const unsigned short* __restrict__ h, const float* __restrict__ dinv,
        const int* __restrict__ rowstart, const int* __restrict__ csr,
        const float* __restrict__ bias,
        unsigned short* __restrict__ outb, int N,
        float* __restrict__ sums, float* __restrict__ sumsq) {
    static_assert(!BNS || D == 128, "BNS path assumes LPR=16 (4 rows/wave)");
    constexpr int LPR = D / 8;           // lanes per row: 16 (D=128) / 8 (D=64)
    constexpr int RPB = 256 / LPR;       // rows per block: 16 / 32
    int lane = threadIdx.x & (LPR - 1);
    int r    = threadIdx.x / LPR;
    int v = blockIdx.x * RPB + r;
    bool valid = v < N;
    if (!BNS && !valid) return;          // BNS path keeps all lanes for shfl
    int vc = valid ? v : N - 1;
    int c0 = lane * 8;
    const unsigned short* hc = h + c0;
    float dv = dinv[vc];

    float acc[8] = {0.f,0.f,0.f,0.f,0.f,0.f,0.f,0.f};
    add8(acc, *(const uint4*)&hc[(size_t)vc * D]);   // self-loop term

    int j  = rowstart[vc];
    int j1 = valid ? rowstart[vc + 1] : j;
    for (; j + 8 <= j1; j += 8) {
        int   s[8]; uint4 q[8];
        #pragma unroll
        for (int i = 0; i < 8; ++i) s[i] = csr[j + i];
        #pragma unroll
        for (int i = 0; i < 8; ++i) q[i] = *(const uint4*)&hc[(size_t)s[i] * D];
        #pragma unroll
        for (int i = 0; i < 8; ++i) add8(acc, q[i]);
    }
    for (; j + 4 <= j1; j += 4) {
        int s0 = csr[j],     s1 = csr[j + 1];
        int s2 = csr[j + 2], s3 = csr[j + 3];
        uint4 q0 = *(const uint4*)&hc[(size_t)s0 * D];
        uint4 q1 = *(const uint4*)&hc[(size_t)s1 * D];
        uint4 q2 = *(const uint4*)&hc[(size_t)s2 * D];
        uint4 q3 = *(const uint4*)&hc[(size_t)s3 * D];
        add8(acc, q0); add8(acc, q1); add8(acc, q2); add8(acc, q3);
    }
    for (; j < j1; ++j) {
        int s = csr[j];
        add8(acc, *(const uint4*)&hc[(size_t)s * D]);
    }

    float4 b0 = *(const float4*)&bias[c0];
    float4 b1 = *(const float4*)&bias[c0 + 4];
    float o[8];
    o[0] = fmaf(acc[0], dv, b0.x); o[1] = fmaf(acc[1], dv, b0.y);
    o[2] = fmaf(acc[2], dv, b0.z); o[3] = fmaf(acc[3], dv, b0.w);
    o[4] = fmaf(acc[4], dv, b1.x); o[5] = fmaf(acc[5], dv, b1.y);
    o[6] = fmaf(acc[6], dv, b1.z); o[7] = fmaf(acc[7], dv, b1.w);
    if (valid) {
        uint4 ov;
        ov.x = pack2bf(o[0], o[1]); ov.y = pack2bf(o[2], o[3]);
        ov.z = pack2bf(o[4], o[5]); ov.w = pack2bf(o[6], o[7]);
        *(uint4*)&outb[(size_t)v * D + c0] = ov;
    }

    if (BNS) {
        float sv[8], qv[8];
        #pragma unroll
        for (int i = 0; i < 8; ++i) {
            sv[i] = valid ? o[i] : 0.f;
            qv[i] = valid ? o[i] * o[i] : 0.f;
        }
        #pragma unroll
        for (int i = 0; i < 8; ++i) {          // wave-local: rows at lane+16k
            sv[i] += __shfl_xor(sv[i], 16); sv[i] += __shfl_xor(sv[i], 32);
            qv[i] += __shfl_xor(qv[i], 16); qv[i] += __shfl_xor(qv[i], 32);
        }
        if ((threadIdx.x & 48) == 0) {          // lanes 0-15 of each wave
            int l = threadIdx.x & 15;
            int copy = (int)blockIdx.x & (BNC - 1);
            float* sp = sums  + copy * 128 + l * 8;
            float* qp = sumsq + copy * 128 + l * 8;
            #pragma unroll
            for (int i = 0; i < 8; ++i) {
                atomicAdd(&sp[i], sv[i]);
                atomicAdd(&qp[i], qv[i]);
            }
        }
    }
}

// ---------------- Global mean pool (bf16 input, D=64) ----------------
__global__ void pool_bf16_kernel(const unsigned short* __restrict__ x,
                                 const int* __restrict__ batch, int N,
                                 float* __restrict__ psum, int* __restrict__ pcnt) {
    __shared__ float ls[NGRAPH * 64];
    __shared__ int   lc[NGRAPH];
    for (int i = threadIdx.x; i < NGRAPH * 64; i += blockDim.x) ls[i] = 0.f;
    if (threadIdx.x < NGRAPH) lc[threadIdx.x] = 0;
    __syncthreads();
    int total = N * 32;
    for (int idx = blockIdx.x * blockDim.x + threadIdx.x; idx < total;
         idx += gridDim.x * blockDim.x) {
        int v = idx >> 5, cp = idx & 31;
        unsigned u = *(const unsigned*)&x[(size_t)v * 64 + cp * 2];
        float lo, hi; bf2_decode(u, lo, hi);
        int g = batch[v];
        atomicAdd(&ls[g * 64 + cp * 2],     lo);
        atomicAdd(&ls[g * 64 + cp * 2 + 1], hi);
        if (cp == 0) atomicAdd(&lc[g], 1);
    }
    __syncthreads();
    for (int i = threadIdx.x; i < NGRAPH * 64; i += blockDim.x) atomicAdd(&psum[i], ls[i]);
    if (threadIdx.x < NGRAPH) atomicAdd(&pcnt[threadIdx.x], lc[threadIdx.x]);
}

__global__ void pool_final_kernel(const float* __restrict__ psum, const int* __restrict__ pcnt,
                                  float* __restrict__ out) {
    int i = threadIdx.x;
    int g = i >> 6;
    float cnt = (float)max(pcnt[g], 1);
    out[i] = psum[i] / cnt;
}

// ---------------- launch ----------------
extern "C" void kernel_launch(void* const* d_in, const int* in_sizes, int n_in,
                              void* d_out, int out_size, void* d_ws, size_t ws_size,
                              hipStream_t stream) {
    const float* x   = (const float*)d_in[0];
    const int*   ei  = (const int*)d_in[1];
    const int*   bat = (const int*)d_in[2];
    const float* W1  = (const float*)d_in[3];
    const float* b1  = (const float*)d_in[4];
    const float* W2  = (const float*)d_in[5];
    const float* b2  = (const float*)d_in[6];
    const float* W3  = (const float*)d_in[7];
    const float* b3  = (const float*)d_in[8];
    const float* g1  = (const float*)d_in[9];
    const float* be1 = (const float*)d_in[10];
    const float* g2  = (const float*)d_in[11];
    const float* be2 = (const float*)d_in[12];
    float* out = (float*)d_out;

    int N = in_sizes[0] / D_IN;
    int E = in_sizes[1] / 2;
    const int* src = ei;
    const int* dst = ei + E;

    char* p = (char*)d_ws;
    auto alloc = [&](size_t bytes) { char* r = p; p += (bytes + 255) & ~(size_t)255; return r; };
    int NB = (N + SCAN_TPB * SCAN_VPT - 1) / (SCAN_TPB * SCAN_VPT);
    // ---- contiguous zero region: ONE memset covers deg + BN partials + pool ----
    char*  zbase    = p;
    int*   deg      = (int*)  alloc((size_t)N * 4);
    float* sums1    = (float*)alloc((size_t)BNC * 128 * 4);
    float* sumsq1   = (float*)alloc((size_t)BNC * 128 * 4);
    float* sums2    = (float*)alloc((size_t)BNC * 128 * 4);
    float* sumsq2   = (float*)alloc((size_t)BNC * 128 * 4);
    float* psum     = (float*)alloc(NGRAPH * 64 * 4);
    int*   pcnt     = (int*)  alloc(NGRAPH * 4);
    size_t zspan    = (size_t)(p - zbase);
    // ---- rest of workspace ----
    int*   rowstart = (int*)  alloc((size_t)(N + 1) * 4);
    int*   rank     = (int*)  alloc((size_t)E * 4);
    float* dinv     = (float*)alloc((size_t)N * 4);
    int*   bsum     = (int*)  alloc((size_t)NB * 4);
    int*   bprefix  = (int*)  alloc((size_t)NB * 4);
    int*   csr      = (int*)  alloc((size_t)E * 4);
    unsigned short* hb16   = (unsigned short*)alloc((size_t)N * 128 * 2);  // GEMM out
    unsigned short* aggb16 = (unsigned short*)alloc((size_t)N * 128 * 2);  // agg out
    unsigned short* Wt1 = (unsigned short*)alloc((size_t)D_HID * D_IN * 2);
    unsigned short* Wt2 = (unsigned short*)alloc((size_t)D_HID * D_HID * 2);
    unsigned short* Wt3 = (unsigned short*)alloc((size_t)D_OUT_ * D_HID * 2);

    int ebl4 = (E + 1023) / 1024;          // 4 edges/thread kernels
    int gblocks = (N + 63) / 64;
    float invN = 1.0f / (float)N;
    int wtot = D_IN * D_HID + D_HID * D_HID + D_HID * D_OUT_;
    int WB = (wtot + 255) / 256;

    // ---- single memset; fused weight-prep + degree/rank count ----
    (void)hipMemsetAsync(zbase, 0, zspan, stream);
    prep_count_kernel<<<WB + ebl4, 256, 0, stream>>>(W1, W2, W3, Wt1, Wt2, Wt3,
                                                     WB, dst, E, deg, rank);

    // ---- CSR scan + scatter (r5-proven structure) ----
    dinv_bsum_kernel<<<NB, SCAN_TPB, 0, stream>>>(deg, N, dinv, bsum);
    scan_bsum_kernel<<<1, SCAN_TPB, 0, stream>>>(bsum, NB, bprefix, rowstart, N, E);
    local_scan_kernel<<<NB, SCAN_TPB, 0, stream>>>(deg, N, bprefix, rowstart);
    scatter_kernel<<<ebl4, 256, 0, stream>>>(src, dst, E, rowstart, rank, csr);

    // ---- Layer 1 (agg writes BN partials; no bn_stats dispatch) ----
    gemm_mfma_kernel<D_IN, D_HID, 0, 0><<<gblocks, 256, 0, stream>>>(
        x, Wt1, hb16, N, dinv, nullptr, nullptr, nullptr, nullptr, 0.f);
    agg_bf16_kernel<D_HID, 1><<<(N + 15) / 16, 256, 0, stream>>>(
        hb16, dinv, rowstart, csr, b1, aggb16, N, sums1, sumsq1);

    // ---- Layer 2 (BN-final + ReLU fused into GEMM; agg writes BN partials) ----
    gemm_mfma_kernel<D_HID, D_HID, 1, 1><<<gblocks, 256, 0, stream>>>(
        aggb16, Wt2, hb16, N, dinv, sums1, sumsq1, g1, be1, invN);
    agg_bf16_kernel<D_HID, 1><<<(N + 15) / 16, 256, 0, stream>>>(
        hb16, dinv, rowstart, csr, b2, aggb16, N, sums2, sumsq2);

    // ---- Layer 3 ----
    gemm_mfma_kernel<D_HID, D_OUT_, 1, 1><<<gblocks, 256, 0, stream>>>(
        aggb16, Wt3, hb16, N, dinv, sums2, sumsq2, g2, be2, invN);
    agg_bf16_kernel<D_OUT_, 0><<<(N + 31) / 32, 256, 0, stream>>>(
        hb16, dinv, rowstart, csr, b3, aggb16, N, nullptr, nullptr);

    // ---- Pool (r5-proven separate kernels) ----
    pool_bf16_kernel<<<256, 256, 0, stream>>>(aggb16, bat, N, psum, pcnt);
    pool_final_kernel<<<1, NGRAPH * 64, 0, stream>>>(psum, pcnt, out);
}

// Round 8
// 343.597 us; speedup vs baseline: 1.4577x; 1.4577x over previous
//
#include <hip/hip_runtime.h>
#include <hip/hip_bf16.h>

#define D_IN   256
#define D_HID  128
#define D_OUT_ 64
#define NGRAPH 16
#define BN_EPS 1e-5f

#define SCAN_TPB 256
#define SCAN_VPT 4            // 1024 elements per block

typedef __attribute__((ext_vector_type(8))) short short8;
typedef __attribute__((ext_vector_type(4))) float floatx4;

// ---------------- helpers ----------------
__device__ __forceinline__ unsigned short f2bf(float x) {   // RNE f32->bf16
    unsigned u = __float_as_uint(x);
    return (unsigned short)((u + 0x7fffu + ((u >> 16) & 1u)) >> 16);
}
__device__ __forceinline__ unsigned pack2bf(float lo, float hi) {
    return (unsigned)f2bf(lo) | ((unsigned)f2bf(hi) << 16);
}
__device__ __forceinline__ void bf2_decode(unsigned u, float& lo, float& hi) {
    lo = __uint_as_float(u << 16);
    hi = __uint_as_float(u & 0xffff0000u);
}
// acc[0..7] += bf16x8(qv)   (h rows are pre-scaled by dinv[src] in the GEMM
// epilogue, so aggregation is an UNWEIGHTED sum — no dinv gather needed)
__device__ __forceinline__ void add8(float* acc, uint4 qv) {
    float f0,f1,f2,f3,f4,f5,f6,f7;
    bf2_decode(qv.x, f0, f1); bf2_decode(qv.y, f2, f3);
    bf2_decode(qv.z, f4, f5); bf2_decode(qv.w, f6, f7);
    acc[0]+=f0; acc[1]+=f1; acc[2]+=f2; acc[3]+=f3;
    acc[4]+=f4; acc[5]+=f5; acc[6]+=f6; acc[7]+=f7;
}

// ---------------- fused weight-prep + degree/rank count (block-split) ----------
// blocks [0,WB): W[K][NOUT] f32 -> Wt[NOUT][K] bf16 ; blocks [WB,..): deg+rank.
// NOTE: no __shared__ here — both halves run at full occupancy (r4 lesson:
// never block-split a big-LDS body with a latency-bound body).
__global__ void prep_count_kernel(const float* __restrict__ W1, const float* __restrict__ W2,
                                  const float* __restrict__ W3,
                                  unsigned short* __restrict__ Wt1,
                                  unsigned short* __restrict__ Wt2,
                                  unsigned short* __restrict__ Wt3, int WB,
                                  const int* __restrict__ dst, int E,
                                  int* __restrict__ deg, int* __restrict__ rank) {
    if ((int)blockIdx.x < WB) {
        int idx = blockIdx.x * 256 + threadIdx.x;
        const int S1 = D_IN * D_HID;          // 32768
        const int S2 = D_HID * D_HID;         // 16384
        const int S3 = D_HID * D_OUT_;        // 8192
        if (idx < S1) {
            int k = idx / D_HID, n = idx - k * D_HID;
            Wt1[(size_t)n * D_IN + k] = f2bf(W1[idx]);
        } else if (idx < S1 + S2) {
            int i = idx - S1;
            int k = i / D_HID, n = i - k * D_HID;
            Wt2[(size_t)n * D_HID + k] = f2bf(W2[i]);
        } else if (idx < S1 + S2 + S3) {
            int i = idx - S1 - S2;
            int k = i / D_OUT_, n = i - k * D_OUT_;
            Wt3[(size_t)n * D_HID + k] = f2bf(W3[i]);
        }
    } else {
        int e0 = ((int)blockIdx.x - WB) * (256 * 4) + threadIdx.x;
        int d[4];
        #pragma unroll
        for (int i = 0; i < 4; ++i) {
            int e = e0 + i * 256;
            if (e < E) d[i] = dst[e];
        }
        #pragma unroll
        for (int i = 0; i < 4; ++i) {
            int e = e0 + i * 256;
            if (e < E) rank[e] = atomicAdd(&deg[d[i]], 1);
        }
    }
}

// fused: dinv for 1024 nodes + block sum for the scan (both depend only on deg)
__global__ void dinv_bsum_kernel(const int* __restrict__ deg, int N,
                                 float* __restrict__ dinv, int* __restrict__ bsum) {
    __shared__ int red[SCAN_TPB];
    int t = threadIdx.x;
    int base = blockIdx.x * (SCAN_TPB * SCAN_VPT) + t;
    int s = 0;
    #pragma unroll
    for (int i = 0; i < SCAN_VPT; ++i) {
        int idx = base + i * SCAN_TPB;
        if (idx < N) {
            int d = deg[idx];
            dinv[idx] = rsqrtf((float)(d + 1));   // +1 self-loop
            s += d;
        }
    }
    red[t] = s;
    __syncthreads();
    for (int off = SCAN_TPB / 2; off > 0; off >>= 1) {
        if (t < off) red[t] += red[t + off];
        __syncthreads();
    }
    if (t == 0) bsum[blockIdx.x] = red[0];
}

__global__ void scan_bsum_kernel(const int* __restrict__ bsum, int NB,
                                 int* __restrict__ bprefix,
                                 int* __restrict__ rowstart, int N, int E) {
    __shared__ int part[SCAN_TPB];
    int t = threadIdx.x;
    int s = (t < NB) ? bsum[t] : 0;
    part[t] = s;
    __syncthreads();
    for (int off = 1; off < SCAN_TPB; off <<= 1) {
        int x = (t >= off) ? part[t - off] : 0;
        __syncthreads();
        part[t] += x;
        __syncthreads();
    }
    if (t < NB) bprefix[t] = part[t] - s;   // exclusive prefix of block sums
    if (t == 0) rowstart[N] = E;            // total degree == E analytically
}

__global__ void local_scan_kernel(const int* __restrict__ deg, int N,
                                  const int* __restrict__ bprefix,
                                  int* __restrict__ rowstart) {
    __shared__ int part[SCAN_TPB];
    int t = threadIdx.x;
    int base = blockIdx.x * (SCAN_TPB * SCAN_VPT) + t * SCAN_VPT;
    int v[SCAN_VPT];
    int s = 0;
    #pragma unroll
    for (int i = 0; i < SCAN_VPT; ++i) {
        v[i] = (base + i < N) ? deg[base + i] : 0;
        s += v[i];
    }
    part[t] = s;
    __syncthreads();
    for (int off = 1; off < SCAN_TPB; off <<= 1) {   // inclusive Hillis-Steele
        int x = (t >= off) ? part[t - off] : 0;
        __syncthreads();
        part[t] += x;
        __syncthreads();
    }
    int excl = part[t] - s + bprefix[blockIdx.x];
    #pragma unroll
    for (int i = 0; i < SCAN_VPT; ++i) {
        if (base + i < N) rowstart[base + i] = excl;
        excl += v[i];
    }
}

// ---------------- MFMA GEMM body: Cb[M][NOUT] bf16 = act(A)[M][K] @ Wt^T * dscale --
// B (Wt) staged into LDS once per block with XOR bank-swizzle (byte ^= (n&7)<<4,
// both write and read sides — involution). Inner loop ds_read_b128 -> MFMA.
// Epilogue scales row v by dscale[v] (= dinv[v]) so the aggregation becomes an
// unweighted sum (no dinv gather per edge).
// FUSE: BN scale/shift computed per block from raw sums/sumsq into LDS.
// Layouts: A[m=lane&15][k=quad*8+j], B[k=quad*8+j][n=lane&15], C/D col=lane&15 row=quad*4+reg.
template<int K, int NOUT, int FUSE, int ABF16>
__device__ __forceinline__ void gemm_body(
        int bid, const void* __restrict__ Aptr, const unsigned short* __restrict__ Wt,
        unsigned short* __restrict__ Cb, int M, const float* __restrict__ dscale,
        const float* __restrict__ sums, const float* __restrict__ sumsq,
        const float* __restrict__ gam, const float* __restrict__ bet, float invN) {
    constexpr int NT = NOUT / 16;
    constexpr int KS = K / 32;
    constexpr int CHUNKS = NOUT * K / 8;      // 16B chunks of Wt
    constexpr int KROW16 = K / 8;             // chunks per Wt row
    __shared__ unsigned short s_wt[NOUT * K];
    __shared__ float s_sc[FUSE ? K : 1];
    __shared__ float s_sh[FUSE ? K : 1];

    int lane = threadIdx.x & 63;
    int wave = threadIdx.x >> 6;
    int col  = lane & 15;
    int quad = lane >> 4;
    int kq   = quad * 8;
    int row  = bid * 64 + wave * 16 + col;
    int rowc = min(row, M - 1);

    // ---- issue A loads FIRST (HBM latency overlaps staging + barrier) ----
    uint4  qa[ABF16 ? KS : 1];
    float4 a0[ABF16 ? 1 : KS], a1[ABF16 ? 1 : KS];
    if (ABF16) {
        const unsigned short* Ab = (const unsigned short*)Aptr;
        #pragma unroll
        for (int i = 0; i < KS; ++i)
            qa[i] = *(const uint4*)&Ab[(size_t)rowc * K + i * 32 + kq];
    } else {
        const float* Af = (const float*)Aptr;
        #pragma unroll
        for (int i = 0; i < KS; ++i) {
            a0[i] = *(const float4*)&Af[(size_t)rowc * K + i * 32 + kq];
            a1[i] = *(const float4*)&Af[(size_t)rowc * K + i * 32 + kq + 4];
        }
    }

    // ---- stage Wt -> LDS with XOR swizzle (read side matches) ----
    {
        const uint4* Wg = (const uint4*)Wt;
        #pragma unroll
        for (int it = 0; it < CHUNKS / 256; ++it) {
            int c = it * 256 + (int)threadIdx.x;
            uint4 v = Wg[c];
            int n = c / KROW16;                       // Wt row of this chunk
            unsigned byte = ((unsigned)c * 16u) ^ ((unsigned)(n & 7) << 4);
            *(uint4*)((char*)s_wt + byte) = v;
        }
    }
    if (FUSE) {
        int t = threadIdx.x;
        if (t < K) {
            float mu  = sums[t] * invN;
            float var = sumsq[t] * invN - mu * mu;
            float sc  = gam[t] * rsqrtf(var + BN_EPS);
            s_sc[t] = sc;
            s_sh[t] = fmaf(-mu, sc, bet[t]);
        }
    }
    __syncthreads();

    // ---- convert A (and apply BN+ReLU when FUSE) ----
    short8 afr[KS];
    if (ABF16) {
        #pragma unroll
        for (int i = 0; i < KS; ++i) {
            if (FUSE) {
                int kb = i * 32 + kq;
                float f0,f1,f2,f3,f4,f5,f6,f7;
                bf2_decode(qa[i].x, f0, f1); bf2_decode(qa[i].y, f2, f3);
                bf2_decode(qa[i].z, f4, f5); bf2_decode(qa[i].w, f6, f7);
                float4 sc0 = *(const float4*)&s_sc[kb];
                float4 sc1 = *(const float4*)&s_sc[kb + 4];
                float4 sh0 = *(const float4*)&s_sh[kb];
                float4 sh1 = *(const float4*)&s_sh[kb + 4];
                f0 = fmaxf(0.f, fmaf(f0, sc0.x, sh0.x));
                f1 = fmaxf(0.f, fmaf(f1, sc0.y, sh0.y));
                f2 = fmaxf(0.f, fmaf(f2, sc0.z, sh0.z));
                f3 = fmaxf(0.f, fmaf(f3, sc0.w, sh0.w));
                f4 = fmaxf(0.f, fmaf(f4, sc1.x, sh1.x));
                f5 = fmaxf(0.f, fmaf(f5, sc1.y, sh1.y));
                f6 = fmaxf(0.f, fmaf(f6, sc1.z, sh1.z));
                f7 = fmaxf(0.f, fmaf(f7, sc1.w, sh1.w));
                uint4 p;
                p.x = pack2bf(f0, f1); p.y = pack2bf(f2, f3);
                p.z = pack2bf(f4, f5); p.w = pack2bf(f6, f7);
                afr[i] = __builtin_bit_cast(short8, p);
            } else {
                afr[i] = __builtin_bit_cast(short8, qa[i]);
            }
        }
    } else {
        #pragma unroll
        for (int i = 0; i < KS; ++i) {
            uint4 p;
            p.x = pack2bf(a0[i].x, a0[i].y); p.y = pack2bf(a0[i].z, a0[i].w);
            p.z = pack2bf(a1[i].x, a1[i].y); p.w = pack2bf(a1[i].z, a1[i].w);
            afr[i] = __builtin_bit_cast(short8, p);
        }
    }

    floatx4 acc[NT];
    #pragma unroll
    for (int nt = 0; nt < NT; ++nt) acc[nt] = (floatx4){0.f, 0.f, 0.f, 0.f};

    // ---- inner loop: ds_read_b128 (swizzled) -> MFMA; pipelined via lgkmcnt ----
    #pragma unroll
    for (int i = 0; i < KS; ++i) {
        #pragma unroll
        for (int nt = 0; nt < NT; ++nt) {
            unsigned byte = ((unsigned)((nt * 16 + col) * K + i * 32 + kq)) * 2u;
            byte ^= (unsigned)(col & 7) << 4;      // (nt*16+col)&7 == col&7
            short8 bfrag = *(const short8*)&*(const unsigned short*)((const char*)s_wt + byte);
            acc[nt] = __builtin_amdgcn_mfma_f32_16x16x32_bf16(afr[i], bfrag, acc[nt], 0, 0, 0);
        }
    }

    int obase = bid * 64 + wave * 16 + quad * 4;
    #pragma unroll
    for (int r = 0; r < 4; ++r) {
        int orow = obase + r;
        if (orow < M) {
            float ds = dscale[orow];
            #pragma unroll
            for (int nt = 0; nt < NT; ++nt)
                Cb[(size_t)orow * NOUT + nt * 16 + col] = f2bf(acc[nt][r] * ds);
        }
    }
}

template<int K, int NOUT, int FUSE, int ABF16>
__global__ __launch_bounds__(256, 2) void gemm_mfma_kernel(
        const void* __restrict__ Aptr, const unsigned short* __restrict__ Wt,
        unsigned short* __restrict__ Cb, int M, const float* __restrict__ dscale,
        const float* __restrict__ sums, const float* __restrict__ sumsq,
        const float* __restrict__ gam, const float* __restrict__ bet, float invN) {
    gemm_body<K, NOUT, FUSE, ABF16>(blockIdx.x, Aptr, Wt, Cb, M, dscale,
                                    sums, sumsq, gam, bet, invN);
}

// ---- layer-1 GEMM with CSR-scatter TAIL inside each block -----------------------
// r0 showed scatter rides free in gemm1's shadow; r4 showed separate scatter
// blocks get poisoned by the static LDS reservation. Fix: every GEMM block
// handles its 1024-edge slice AFTER its C-store — same blocks, LDS already
// paid, tail latency overlapped by co-resident blocks' GEMM work.
__global__ __launch_bounds__(256, 2) void gemm1_scattail_kernel(
        const float* __restrict__ x, const unsigned short* __restrict__ Wt1,
        unsigned short* __restrict__ Cb, int M, const float* __restrict__ dscale,
        const int* __restrict__ src, const int* __restrict__ dst, int E,
        const int* __restrict__ rowstart, const int* __restrict__ rank,
        int* __restrict__ csr) {
    gemm_body<D_IN, D_HID, 0, 0>(blockIdx.x, x, Wt1, Cb, M, dscale,
                                 nullptr, nullptr, nullptr, nullptr, 0.f);
    // ---- scatter tail: 4 edges/thread, atomic-free (rank precomputed) ----
    int e0 = (int)blockIdx.x * (256 * 4) + threadIdx.x;
    int d[4], rk[4], sv[4], pos[4];
    #pragma unroll
    for (int i = 0; i < 4; ++i) {
        int e = e0 + i * 256;
        if (e < E) { d[i] = dst[e]; rk[i] = rank[e]; sv[i] = src[e]; }
    }
    #pragma unroll
    for (int i = 0; i < 4; ++i) {
        int e = e0 + i * 256;
        if (e < E) pos[i] = rowstart[d[i]];
    }
    #pragma unroll
    for (int i = 0; i < 4; ++i) {
        int e = e0 + i * 256;
        if (e < E) csr[pos[i] + rk[i]] = sv[i];
    }
}

// ---------------- Aggregation (pre-scaled bf16 h, bf16 out, 4B CSR) ---------------
// out[v] = dinv[v] * (h[v] + sum_{s in N(v)} h[s]) + bias     (h pre-scaled by dinv)
// Barrier-free, early-return (r3/r7/r9 lesson: no __syncthreads, no fused stats,
// no global atomics from this 3125-block grid — ever).
template<int D>
__global__ __launch_bounds__(256) void agg_bf16_kernel(
        const unsigned short* __restrict__ h, const float* __restrict__ dinv,
        const int* __restrict__ rowstart, const int* __restrict__ csr,
        const float* __restrict__ bias,
        unsigned short* __restrict__ outb, int N) {
    constexpr int LPR = D / 8;           // lanes per row: 16 (D=128) / 8 (D=64)
    constexpr int RPB = 256 / LPR;       // rows per block: 16 / 32
    int lane = threadIdx.x & (LPR - 1);
    int r    = threadIdx.x / LPR;
    int v = blockIdx.x * RPB + r;
    if (v >= N) return;
    int c0 = lane * 8;
    const unsigned short* hc = h + c0;
    float dv = dinv[v];

    float acc[8] = {0.f,0.f,0.f,0.f,0.f,0.f,0.f,0.f};
    add8(acc, *(const uint4*)&hc[(size_t)v * D]);    // self-loop term

    int j  = rowstart[v];
    int j1 = rowstart[v + 1];
    for (; j + 8 <= j1; j += 8) {
        int   s[8]; uint4 q[8];
        #pragma unroll
        for (int i = 0; i < 8; ++i) s[i] = csr[j + i];
        #pragma unroll
        for (int i = 0; i < 8; ++i) q[i] = *(const uint4*)&hc[(size_t)s[i] * D];
        #pragma unroll
        for (int i = 0; i < 8; ++i) add8(acc, q[i]);
    }
    for (; j + 4 <= j1; j += 4) {
        int s0 = csr[j],     s1 = csr[j + 1];
        int s2 = csr[j + 2], s3 = csr[j + 3];
        uint4 q0 = *(const uint4*)&hc[(size_t)s0 * D];
        uint4 q1 = *(const uint4*)&hc[(size_t)s1 * D];
        uint4 q2 = *(const uint4*)&hc[(size_t)s2 * D];
        uint4 q3 = *(const uint4*)&hc[(size_t)s3 * D];
        add8(acc, q0); add8(acc, q1); add8(acc, q2); add8(acc, q3);
    }
    for (; j < j1; ++j) {
        int s = csr[j];
        add8(acc, *(const uint4*)&hc[(size_t)s * D]);
    }

    float4 b0 = *(const float4*)&bias[c0];
    float4 b1 = *(const float4*)&bias[c0 + 4];
    float o0 = fmaf(acc[0], dv, b0.x), o1 = fmaf(acc[1], dv, b0.y);
    float o2 = fmaf(acc[2], dv, b0.z), o3 = fmaf(acc[3], dv, b0.w);
    float o4 = fmaf(acc[4], dv, b1.x), o5 = fmaf(acc[5], dv, b1.y);
    float o6 = fmaf(acc[6], dv, b1.z), o7 = fmaf(acc[7], dv, b1.w);
    uint4 o;
    o.x = pack2bf(o0, o1); o.y = pack2bf(o2, o3);
    o.z = pack2bf(o4, o5); o.w = pack2bf(o6, o7);
    *(uint4*)&outb[(size_t)v * D + c0] = o;
}

// ---------------- BatchNorm stats (bf16 input, D=128) ----------------
__global__ void bn_stats_bf16_kernel(const unsigned short* __restrict__ x, int N,
                                     float* __restrict__ sums, float* __restrict__ sumsq) {
    __shared__ float ls0[256], ls1[256], lq0[256], lq1[256];
    int pr = threadIdx.x & 63;           // channel pair
    int rg = threadIdx.x >> 6;           // row group 0..3
    float s0=0.f, s1=0.f, q0=0.f, q1=0.f;
    for (int v = blockIdx.x * 4 + rg; v < N; v += gridDim.x * 4) {
        unsigned u = *(const unsigned*)&x[(size_t)v * 128 + pr * 2];
        float lo, hi; bf2_decode(u, lo, hi);
        s0 += lo; s1 += hi;
        q0 = fmaf(lo, lo, q0); q1 = fmaf(hi, hi, q1);
    }
    ls0[threadIdx.x]=s0; ls1[threadIdx.x]=s1; lq0[threadIdx.x]=q0; lq1[threadIdx.x]=q1;
    __syncthreads();
    if (threadIdx.x < 64) {
        int pp = threadIdx.x;
        float a0=0,a1=0,b0=0,b1=0;
        #pragma unroll
        for (int g = 0; g < 4; ++g) {
            a0 += ls0[g*64+pp]; a1 += ls1[g*64+pp];
            b0 += lq0[g*64+pp]; b1 += lq1[g*64+pp];
        }
        atomicAdd(&sums[pp*2],  a0); atomicAdd(&sums[pp*2+1],  a1);
        atomicAdd(&sumsq[pp*2], b0); atomicAdd(&sumsq[pp*2+1], b1);
    }
}

// ---------------- Global mean pool (bf16 input, D=64) ----------------
__global__ void pool_bf16_kernel(const unsigned short* __restrict__ x,
                                 const int* __restrict__ batch, int N,
                                 float* __restrict__ psum, int* __restrict__ pcnt) {
    __shared__ float ls[NGRAPH * 64];
    __shared__ int   lc[NGRAPH];
    for (int i = threadIdx.x; i < NGRAPH * 64; i += blockDim.x) ls[i] = 0.f;
    if (threadIdx.x < NGRAPH) lc[threadIdx.x] = 0;
    __syncthreads();
    int total = N * 32;
    for (int idx = blockIdx.x * blockDim.x + threadIdx.x; idx < total;
         idx += gridDim.x * blockDim.x) {
        int v = idx >> 5, cp = idx & 31;
        unsigned u = *(const unsigned*)&x[(size_t)v * 64 + cp * 2];
        float lo, hi; bf2_decode(u, lo, hi);
        int g = batch[v];
        atomicAdd(&ls[g * 64 + cp * 2],     lo);
        atomicAdd(&ls[g * 64 + cp * 2 + 1], hi);
        if (cp == 0) atomicAdd(&lc[g], 1);
    }
    __syncthreads();
    for (int i = threadIdx.x; i < NGRAPH * 64; i += blockDim.x) atomicAdd(&psum[i], ls[i]);
    if (threadIdx.x < NGRAPH) atomicAdd(&pcnt[threadIdx.x], lc[threadIdx.x]);
}

__global__ void pool_final_kernel(const float* __restrict__ psum, const int* __restrict__ pcnt,
                                  float* __restrict__ out) {
    int i = threadIdx.x;
    int g = i >> 6;
    float cnt = (float)max(pcnt[g], 1);
    out[i] = psum[i] / cnt;
}

// ---------------- launch ----------------
extern "C" void kernel_launch(void* const* d_in, const int* in_sizes, int n_in,
                              void* d_out, int out_size, void* d_ws, size_t ws_size,
                              hipStream_t stream) {
    const float* x   = (const float*)d_in[0];
    const int*   ei  = (const int*)d_in[1];
    const int*   bat = (const int*)d_in[2];
    const float* W1  = (const float*)d_in[3];
    const float* b1  = (const float*)d_in[4];
    const float* W2  = (const float*)d_in[5];
    const float* b2  = (const float*)d_in[6];
    const float* W3  = (const float*)d_in[7];
    const float* b3  = (const float*)d_in[8];
    const float* g1  = (const float*)d_in[9];
    const float* be1 = (const float*)d_in[10];
    const float* g2  = (const float*)d_in[11];
    const float* be2 = (const float*)d_in[12];
    float* out = (float*)d_out;

    int N = in_sizes[0] / D_IN;
    int E = in_sizes[1] / 2;
    const int* src = ei;
    const int* dst = ei + E;

    char* p = (char*)d_ws;
    auto alloc = [&](size_t bytes) { char* r = p; p += (bytes + 255) & ~(size_t)255; return r; };
    int NB = (N + SCAN_TPB * SCAN_VPT - 1) / (SCAN_TPB * SCAN_VPT);
    // ---- contiguous zero region: ONE memset covers deg + BN ping-pong + pool ----
    char*  zbase    = p;
    int*   deg      = (int*)  alloc((size_t)N * 4);
    float* sums1    = (float*)alloc(128 * 4);
    float* sumsq1   = (float*)alloc(128 * 4);
    float* sums2    = (float*)alloc(128 * 4);
    float* sumsq2   = (float*)alloc(128 * 4);
    float* psum     = (float*)alloc(NGRAPH * 64 * 4);
    int*   pcnt     = (int*)  alloc(NGRAPH * 4);
    size_t zspan    = (size_t)(p - zbase);
    // ---- rest of workspace ----
    int*   rowstart = (int*)  alloc((size_t)(N + 1) * 4);
    int*   rank     = (int*)  alloc((size_t)E * 4);
    float* dinv     = (float*)alloc((size_t)N * 4);
    int*   bsum     = (int*)  alloc((size_t)NB * 4);
    int*   bprefix  = (int*)  alloc((size_t)NB * 4);
    int*   csr      = (int*)  alloc((size_t)E * 4);
    unsigned short* hb16   = (unsigned short*)alloc((size_t)N * 128 * 2);  // GEMM out
    unsigned short* aggb16 = (unsigned short*)alloc((size_t)N * 128 * 2);  // agg out
    unsigned short* Wt1 = (unsigned short*)alloc((size_t)D_HID * D_IN * 2);
    unsigned short* Wt2 = (unsigned short*)alloc((size_t)D_HID * D_HID * 2);
    unsigned short* Wt3 = (unsigned short*)alloc((size_t)D_OUT_ * D_HID * 2);

    int ebl4 = (E + 1023) / 1024;          // 4 edges/thread kernels
    int gblocks = (N + 63) / 64;
    int g1blocks = max(gblocks, ebl4);     // gemm1 grid must cover both rows & edges
    float invN = 1.0f / (float)N;
    int wtot = D_IN * D_HID + D_HID * D_HID + D_HID * D_OUT_;
    int WB = (wtot + 255) / 256;

    // ---- single memset; fused weight-prep + degree/rank count ----
    (void)hipMemsetAsync(zbase, 0, zspan, stream);
    prep_count_kernel<<<WB + ebl4, 256, 0, stream>>>(W1, W2, W3, Wt1, Wt2, Wt3,
                                                     WB, dst, E, deg, rank);

    // ---- CSR scan (r5-proven structure) ----
    dinv_bsum_kernel<<<NB, SCAN_TPB, 0, stream>>>(deg, N, dinv, bsum);
    scan_bsum_kernel<<<1, SCAN_TPB, 0, stream>>>(bsum, NB, bprefix, rowstart, N, E);
    local_scan_kernel<<<NB, SCAN_TPB, 0, stream>>>(deg, N, bprefix, rowstart);

    // ---- Layer 1: GEMM with scatter tail (scatter dispatch removed) ----
    gemm1_scattail_kernel<<<g1blocks, 256, 0, stream>>>(
        x, Wt1, hb16, N, dinv, src, dst, E, rowstart, rank, csr);
    agg_bf16_kernel<D_HID><<<(N + 15) / 16, 256, 0, stream>>>(
        hb16, dinv, rowstart, csr, b1, aggb16, N);
    bn_stats_bf16_kernel<<<256, 256, 0, stream>>>(aggb16, N, sums1, sumsq1);

    // ---- Layer 2 (BN-final + ReLU fused into GEMM) ----
    gemm_mfma_kernel<D_HID, D_HID, 1, 1><<<gblocks, 256, 0, stream>>>(
        aggb16, Wt2, hb16, N, dinv, sums1, sumsq1, g1, be1, invN);
    agg_bf16_kernel<D_HID><<<(N + 15) / 16, 256, 0, stream>>>(
        hb16, dinv, rowstart, csr, b2, aggb16, N);
    bn_stats_bf16_kernel<<<256, 256, 0, stream>>>(aggb16, N, sums2, sumsq2);

    // ---- Layer 3 ----
    gemm_mfma_kernel<D_HID, D_OUT_, 1, 1><<<gblocks, 256, 0, stream>>>(
        aggb16, Wt3, hb16, N, dinv, sums2, sumsq2, g2, be2, invN);
    agg_bf16_kernel<D_OUT_><<<(N + 31) / 32, 256, 0, stream>>>(
        hb16, dinv, rowstart, csr, b3, aggb16, N);

    // ---- Pool (r5-proven separate kernels) ----
    pool_bf16_kernel<<<256, 256, 0, stream>>>(aggb16, bat, N, psum, pcnt);
    pool_final_kernel<<<1, NGRAPH * 64, 0, stream>>>(psum, pcnt, out);
}